// Round 1
// baseline (89.679 us; speedup 1.0000x reference)
//
#include <hip/hip_runtime.h>

// Problem constants (LX=8, LY=4, D=4, PHYS=2)
#define ETA 0.001f
#define NVEC 16384          // 2 * LX * D^5
#define NB   8192           // LX * D^5

// ---------------------------------------------------------------------------
// Kernel A: delta[b][n] = ETA * ( relu(cfg_b . W1 + b1) . W2[:,n] + b2[n] )
// Grid: (64 n-tiles of 256, ncfg/16 b-tiles).  Each block: 256 n x 16 configs.
// ---------------------------------------------------------------------------
__global__ __launch_bounds__(256) void nn_delta_kernel(
    const int* __restrict__ cfg, const float* __restrict__ W1,
    const float* __restrict__ b1, const float* __restrict__ W2,
    const float* __restrict__ b2, float* __restrict__ delta)
{
    __shared__ float Hs[16][64];
    const int t  = threadIdx.x;
    const int b0 = blockIdx.y * 16;
    const int n  = blockIdx.x * 256 + t;

    // H tile: 16 configs x 64 hidden units (1024 entries, 4 per thread)
    for (int e = t; e < 16 * 64; e += 256) {
        const int bb = e >> 6, k = e & 63;
        float acc = b1[k];
        const int* c = cfg + (b0 + bb) * 32;
        #pragma unroll
        for (int m = 0; m < 32; ++m)
            acc = fmaf((float)c[m], W1[m * 64 + k], acc);
        Hs[bb][k] = fmaxf(acc, 0.0f);
    }
    __syncthreads();

    float acc[16];
    #pragma unroll
    for (int bb = 0; bb < 16; ++bb) acc[bb] = 0.0f;

    #pragma unroll 4
    for (int k = 0; k < 64; ++k) {
        const float w = W2[k * NVEC + n];   // coalesced across lanes
        #pragma unroll
        for (int bb = 0; bb < 16; ++bb)
            acc[bb] = fmaf(Hs[bb][k], w, acc[bb]);   // LDS broadcast
    }
    const float bias = b2[n];
    #pragma unroll
    for (int bb = 0; bb < 16; ++bb)
        delta[(b0 + bb) * NVEC + n] = ETA * (acc[bb] + bias);
}

// ---------------------------------------------------------------------------
// Kernel B: one block per config.
//   1) s[x,y,a,b,c,d] = A[x,y,a,b,c,d, cfg[x,y]]           (LDS, 32 KB)
//   2) vec = [bot | top] + delta                            (LDS, 64 KB)
//        bot[x,(l,L),(r,R),U] = sum_u s[x,0,l,r,0,u] * s[x,1,L,R,u,U]
//        top[x,(l,L),(r,R),d] = sum_u s[x,2,l,r,d,u] * s[x,3,L,R,u,0]
//   3) factored scan:  v'[jJ] = sum_{I,u} (sum_i v[iI]*bot2[x,i,j,u]) * top2[x,I,J,u]
//   out[b] = v[0] after 8 steps.
// ---------------------------------------------------------------------------
__global__ __launch_bounds__(256) void contract_kernel(
    const int* __restrict__ cfg, const float* __restrict__ A,
    const float* __restrict__ delta, float* __restrict__ out)
{
    __shared__ float  s[8192];       // 32 KB
    __shared__ float  vec[NVEC];     // 64 KB
    __shared__ float4 T[256];        // 4 KB: T[I*16 + j]
    __shared__ float  vbuf[2][256];  // 2 KB
    __shared__ int    cfgs[32];

    const int t = threadIdx.x;
    const int b = blockIdx.x;

    if (t < 32) cfgs[t] = cfg[b * 32 + t];
    __syncthreads();

    // ---- 1) gather s ----
    for (int idx = t; idx < 8192; idx += 256)
        s[idx] = A[idx * 2 + cfgs[idx >> 8]];
    __syncthreads();

    // ---- 2) build vec (4096 float4 outputs, 16 per thread) ----
    const float4* dlt = (const float4*)(delta + b * NVEC);
    for (int q = 0; q < 16; ++q) {
        const int m    = q * 256 + t;        // float4 index in vec
        const int half = m >> 11;            // 0 = bot, 1 = top  (wave-uniform)
        const int x    = (m >> 8) & 7;
        const int i    = (m >> 4) & 15;
        const int j    = m & 15;
        const int l = i >> 2, L = i & 3, r = j >> 2, R = j & 3;
        const float* sA = s + (x * 4 + half * 2) * 256;  // y=0 or y=2
        const float* sB = sA + 256;                      // y=1 or y=3

        float4 acc = make_float4(0.f, 0.f, 0.f, 0.f);
        if (half == 0) {
            #pragma unroll
            for (int u = 0; u < 4; ++u) {
                const float  a  = sA[l * 64 + r * 16 + u];            // c=0 fixed
                const float4 bv = *(const float4*)(sB + L * 64 + R * 16 + u * 4);
                acc.x = fmaf(a, bv.x, acc.x);
                acc.y = fmaf(a, bv.y, acc.y);
                acc.z = fmaf(a, bv.z, acc.z);
                acc.w = fmaf(a, bv.w, acc.w);
            }
        } else {
            #pragma unroll
            for (int u = 0; u < 4; ++u) {
                const float bvs = sB[L * 64 + R * 16 + u * 4];        // d=0 fixed
                const int base = l * 64 + r * 16;
                acc.x = fmaf(sA[base +  0 + u], bvs, acc.x);
                acc.y = fmaf(sA[base +  4 + u], bvs, acc.y);
                acc.z = fmaf(sA[base +  8 + u], bvs, acc.z);
                acc.w = fmaf(sA[base + 12 + u], bvs, acc.w);
            }
        }
        const float4 d4 = dlt[m];
        acc.x += d4.x; acc.y += d4.y; acc.z += d4.z; acc.w += d4.w;
        ((float4*)vec)[m] = acc;
    }
    __syncthreads();

    // ---- 3) scan ----
    float* vcur = vbuf[0];
    float* vnxt = vbuf[1];
    vcur[t] = (t == 0) ? 1.0f : 0.0f;
    __syncthreads();

    const float4* bot4 = (const float4*)vec;           // [x*256 + i*16 + j]
    const float4* top4 = (const float4*)(vec + NB);    // [x*256 + I*16 + J]

    for (int x = 0; x < 8; ++x) {
        // phase A: T[I*16+j].u = sum_i vcur[i*16+I] * bot2[x,i,j,u]
        {
            const int I = t >> 4, j = t & 15;
            float4 acc = make_float4(0.f, 0.f, 0.f, 0.f);
            #pragma unroll
            for (int i = 0; i < 16; ++i) {
                const float  vi = vcur[i * 16 + I];
                const float4 bv = bot4[x * 256 + i * 16 + j];
                acc.x = fmaf(vi, bv.x, acc.x);
                acc.y = fmaf(vi, bv.y, acc.y);
                acc.z = fmaf(vi, bv.z, acc.z);
                acc.w = fmaf(vi, bv.w, acc.w);
            }
            T[t] = acc;
        }
        __syncthreads();
        // phase B: vnxt[j*16+J] = sum_I dot(T[I*16+j], top2[x,I,J,:])
        {
            const int j = t >> 4, J = t & 15;
            float acc = 0.f;
            #pragma unroll
            for (int I = 0; I < 16; ++I) {
                const float4 tv = T[I * 16 + j];
                const float4 pv = top4[x * 256 + I * 16 + J];
                acc = fmaf(tv.x, pv.x, acc);
                acc = fmaf(tv.y, pv.y, acc);
                acc = fmaf(tv.z, pv.z, acc);
                acc = fmaf(tv.w, pv.w, acc);
            }
            vnxt[j * 16 + J] = acc;
        }
        __syncthreads();
        float* tmp = vcur; vcur = vnxt; vnxt = tmp;
    }

    if (t == 0) out[b] = vcur[0];
}

// ---------------------------------------------------------------------------
extern "C" void kernel_launch(void* const* d_in, const int* in_sizes, int n_in,
                              void* d_out, int out_size, void* d_ws, size_t ws_size,
                              hipStream_t stream) {
    const int*   cfg = (const int*)  d_in[0];
    const float* A   = (const float*)d_in[1];
    const float* W1  = (const float*)d_in[2];
    const float* b1  = (const float*)d_in[3];
    const float* W2  = (const float*)d_in[4];
    const float* b2  = (const float*)d_in[5];
    float* out   = (float*)d_out;
    float* delta = (float*)d_ws;                  // ncfg * 16384 floats (8 MB)

    const int ncfg = in_sizes[0] / 32;            // 128

    dim3 gA(NVEC / 256, ncfg / 16);               // (64, 8)
    nn_delta_kernel<<<gA, 256, 0, stream>>>(cfg, W1, b1, W2, b2, delta);
    contract_kernel<<<ncfg, 256, 0, stream>>>(cfg, A, delta, out);
}